// Round 8
// baseline (81.705 us; speedup 1.0000x reference)
//
#include <hip/hip_runtime.h>
#include <hip/hip_bf16.h>
#include <math.h>

// DotProductAttention B=32, L=2048, D=64, fp32 IO, per-batch key-length mask.
// Round 8: P-LDS roundtrip eliminated via 16x16x16 MFMA for PV.
//  - Swapped QK^T leaves lane(lq,lg) with S[k=t*16+lg*4+r][q=lq], which IS
//    the 16x16x16 A-frag layout (A[row=lq][kappa=lg*4+r]) for A=P. PV runs
//    as 16x mfma_f32_16x16x16_bf16 with A packed in-register from s[t],
//    B = 4 consecutive shorts from Vt (ds_read_b64). No P LDS at all
//    (round 7's P layout was an 8-way bank conflict: 9.4e6 counts).
//  - Double-buffered K/V staging, single barrier per k-tile (round 7).
//  - LDS 32.3KB/block -> 4 blocks/CU; GRID 768 -> 1024.
//  - LPT queue (longest batches first) retained.

#define BB 32
#define LL 2048
#define DD 64
#define QBLK 64
#define KBLK 64
#define NTILES (BB * (LL / QBLK))   // 1024
#define GRID 1024

typedef __attribute__((ext_vector_type(8))) short bf16x8;
typedef __attribute__((ext_vector_type(4))) short bf16x4;
typedef __attribute__((ext_vector_type(4))) float f32x4;

static __device__ __forceinline__ short f2bf(float f) {
    __hip_bfloat16 h = __float2bfloat16(f);
    return *reinterpret_cast<short*>(&h);
}
static __device__ __forceinline__ unsigned pk2(float a, float b) {
    return (unsigned)(unsigned short)f2bf(a) | ((unsigned)(unsigned short)f2bf(b) << 16);
}
static __device__ __forceinline__ float exp2c(float x) {
    return __builtin_amdgcn_exp2f(x);
}
static __device__ __forceinline__ int kswz(int row) { return (row & 7) << 3; }
static __device__ __forceinline__ int vswz(int d)   { return ((d ^ (d >> 2)) & 7) << 3; }

static __device__ __forceinline__ f32x4 mfma16(bf16x4 a, bf16x4 b, f32x4 c) {
#if __has_builtin(__builtin_amdgcn_mfma_f32_16x16x16bf16_1k)
    return __builtin_amdgcn_mfma_f32_16x16x16bf16_1k(a, b, c, 0, 0, 0);
#else
    asm("v_mfma_f32_16x16x16_bf16 %0, %1, %2, %0" : "+v"(c) : "v"(a), "v"(b));
    return c;
#endif
}

// ws[0] = queue counter; ws[1..32] = batch ids sorted by valid_len desc
__global__ void init_ctr_kernel(const int* __restrict__ vlen, int* __restrict__ ws) {
    int t = threadIdx.x;
    if (t == 0) ws[0] = 0;
    if (t < BB) {
        int v = vlen[t];
        int rank = 0;
        for (int j = 0; j < BB; ++j) {
            int vj = vlen[j];
            rank += (vj > v) || (vj == v && j < t);
        }
        ws[1 + rank] = t;
    }
}

__global__ __launch_bounds__(256, 2) void attn_mfma_kernel(
    const float* __restrict__ Q, const float* __restrict__ K,
    const float* __restrict__ V, const int* __restrict__ vlen,
    float* __restrict__ O, int* __restrict__ ws)
{
    __shared__ __align__(16) short Ks[2][KBLK * DD];   // [buf][k][d], kswz
    __shared__ __align__(16) short Vt[2][DD * KBLK];   // [buf][d][k], vswz
    __shared__ int s_tile;

    int* ctr = ws;
    const int* order = ws + 1;

    const int tid  = threadIdx.x;
    const int wid  = tid >> 6;
    const int lane = tid & 63;
    const int lq   = lane & 15;
    const int lg   = lane >> 4;

    // V staging mapping: thread owns 4 k-rows x 4 d-cols
    const int vd4 = (tid & 15) * 4;     // d base
    const int vkr = (tid >> 4) * 4;     // k base

    const float QSCALE = 0.125f * 1.44269504088896341f;  // 1/sqrt(D) * log2(e)

    float4 kpre[4], vpre[4];

    for (;;) {
        __syncthreads();                 // prev tile fully done before s_tile reuse
        if (tid == 0) s_tile = atomicAdd(ctr, 1);
        __syncthreads();
        const int tile = s_tile;
        if (tile >= NTILES) break;

        const int b     = order[tile >> 5];   // LPT: longest batches first
        const int qt    = tile & 31;
        const int qbase = qt * QBLK + wid * 16;
        const int valid = vlen[b];
        const int ntiles = (valid + KBLK - 1) / KBLK;

        const float4* Kg4 = reinterpret_cast<const float4*>(K + (size_t)b * LL * DD);
        const float4* Vg4 = reinterpret_cast<const float4*>(V + (size_t)b * LL * DD);

        // prefetch K/V k-tile `t` into kpre/vpre
        auto prefetch = [&](int t) {
            const int base4 = t * KBLK * (DD / 4);
            #pragma unroll
            for (int i = 0; i < 4; ++i) kpre[i] = Kg4[base4 + tid + i * 256];
            #pragma unroll
            for (int r = 0; r < 4; ++r) vpre[r] = Vg4[base4 + (vkr + r) * 16 + (tid & 15)];
        };
        // write kpre/vpre (fp32) -> LDS buf (bf16, swizzled)
        auto stage = [&](int buf) {
            short* ks = &Ks[buf][0];
            short* vt = &Vt[buf][0];
            #pragma unroll
            for (int i = 0; i < 4; ++i) {
                int idx = tid + i * 256;
                int kr  = idx >> 4;
                int dc  = (idx & 15) * 4;
                float4 kv = kpre[i];
                int e = (kr * 64 + dc) ^ kswz(kr);
                *reinterpret_cast<uint2*>(&ks[e]) =
                    make_uint2(pk2(kv.x, kv.y), pk2(kv.z, kv.w));
            }
            float4 v0 = vpre[0], v1 = vpre[1], v2 = vpre[2], v3 = vpre[3];
            int e0 = ((vd4 + 0) * 64 + vkr) ^ vswz(vd4 + 0);
            *reinterpret_cast<uint2*>(&vt[e0]) = make_uint2(pk2(v0.x, v1.x), pk2(v2.x, v3.x));
            int e1 = ((vd4 + 1) * 64 + vkr) ^ vswz(vd4 + 1);
            *reinterpret_cast<uint2*>(&vt[e1]) = make_uint2(pk2(v0.y, v1.y), pk2(v2.y, v3.y));
            int e2 = ((vd4 + 2) * 64 + vkr) ^ vswz(vd4 + 2);
            *reinterpret_cast<uint2*>(&vt[e2]) = make_uint2(pk2(v0.z, v1.z), pk2(v2.z, v3.z));
            int e3 = ((vd4 + 3) * 64 + vkr) ^ vswz(vd4 + 3);
            *reinterpret_cast<uint2*>(&vt[e3]) = make_uint2(pk2(v0.w, v1.w), pk2(v2.w, v3.w));
        };

        // ---- Q B-frags (regs): lane holds Q[qbase+lq][ds*32 + lg*8 .. +7]
        bf16x8 qf[2];
        {
            const float* Qr = Q + ((size_t)b * LL + qbase + lq) * DD;
            #pragma unroll
            for (int ds_ = 0; ds_ < 2; ++ds_) {
                const float4* p4 = reinterpret_cast<const float4*>(Qr + ds_ * 32 + lg * 8);
                float4 a = p4[0], c = p4[1];
                bf16x8 f;
                f[0] = f2bf(a.x * QSCALE); f[1] = f2bf(a.y * QSCALE);
                f[2] = f2bf(a.z * QSCALE); f[3] = f2bf(a.w * QSCALE);
                f[4] = f2bf(c.x * QSCALE); f[5] = f2bf(c.y * QSCALE);
                f[6] = f2bf(c.z * QSCALE); f[7] = f2bf(c.w * QSCALE);
                qf[ds_] = f;
            }
        }

        f32x4 acc[4];                    // acc[n][r]: q=lg*4+r, d=n*16+lq
        #pragma unroll
        for (int n = 0; n < 4; ++n) acc[n] = (f32x4){0.f, 0.f, 0.f, 0.f};
        float m_ = -1e30f, l_ = 0.f;     // scalars for q = lq (k-major lanes)

        // ---- pipeline prologue: stage tile 0 into buf 0, prefetch tile 1
        prefetch(0);
        stage(0);
        if (ntiles > 1) prefetch(1);
        __syncthreads();                 // buf0 ready for all waves

        for (int kt = 0; kt < ntiles; ++kt) {
            const int cur = kt & 1;

            // ---- write next tile into other buffer; issue loads for t+2
            if (kt + 1 < ntiles) {
                stage(cur ^ 1);          // kpre/vpre hold tile kt+1 (landed)
                if (kt + 2 < ntiles) prefetch(kt + 2);
            }

            // ---- swapped QK^T: s[t][r] = S[k = kt*64+t*16+lg*4+r][q = lq]
            const short* ks = &Ks[cur][0];
            f32x4 s[4];
            #pragma unroll
            for (int t = 0; t < 4; ++t) {
                f32x4 a = (f32x4){0.f, 0.f, 0.f, 0.f};
                const int krow = t * 16 + lq;
                #pragma unroll
                for (int ds_ = 0; ds_ < 2; ++ds_) {
                    int e = (krow * 64 + ds_ * 32 + lg * 8) ^ kswz(krow);
                    bf16x8 kf = *reinterpret_cast<const bf16x8*>(&ks[e]);
                    a = __builtin_amdgcn_mfma_f32_16x16x32_bf16(kf, qf[ds_], a, 0, 0, 0);
                }
                s[t] = a;
            }

            // ---- mask (last partial tile only), in-lane row-max + 2 shfl
            const bool tail = (kt == ntiles - 1) && (valid & (KBLK - 1));
            if (tail) {
                #pragma unroll
                for (int t = 0; t < 4; ++t)
                    #pragma unroll
                    for (int r = 0; r < 4; ++r) {
                        int kg = kt * KBLK + t * 16 + lg * 4 + r;
                        if (kg >= valid) s[t][r] = -1e30f;
                    }
            }
            float mx = s[0][0];
            #pragma unroll
            for (int t = 0; t < 4; ++t)
                #pragma unroll
                for (int r = 0; r < 4; ++r) mx = fmaxf(mx, s[t][r]);
            mx = fmaxf(mx, __shfl_xor(mx, 16, 64));
            mx = fmaxf(mx, __shfl_xor(mx, 32, 64));

            // ---- defer-max (T13, log2 domain THR=8)
            if (__any(mx - m_ > 8.0f)) {
                float mnew = fmaxf(m_, mx);
                float corr = exp2c(m_ - mnew);
                m_ = mnew;
                l_ *= corr;
                #pragma unroll
                for (int r = 0; r < 4; ++r) {
                    float cq = __shfl(corr, lg * 4 + r, 64);   // corr for q=lg*4+r
                    #pragma unroll
                    for (int n = 0; n < 4; ++n) acc[n][r] *= cq;
                }
            }

            // ---- p = exp2(s - m), in-lane sum + 2 shfl
            float ls = 0.f;
            #pragma unroll
            for (int t = 0; t < 4; ++t)
                #pragma unroll
                for (int r = 0; r < 4; ++r) {
                    float p = exp2c(s[t][r] - m_);
                    s[t][r] = p;
                    ls += p;
                }
            ls += __shfl_xor(ls, 16, 64);
            ls += __shfl_xor(ls, 32, 64);
            l_ += ls;

            // ---- PV via 16x16x16 MFMA: A = P-frag packed in-register
            //      (s layout IS the A-frag layout), B = Vt ds_read_b64.
            const short* vt = &Vt[cur][0];
            #pragma unroll
            for (int t = 0; t < 4; ++t) {
                union { uint2 u; bf16x4 v; } pa;
                pa.u = make_uint2(pk2(s[t][0], s[t][1]), pk2(s[t][2], s[t][3]));
                #pragma unroll
                for (int n = 0; n < 4; ++n) {
                    int drow = n * 16 + lq;
                    int ve = (drow * 64 + t * 16 + lg * 4) ^ vswz(drow);
                    union { uint2 u; bf16x4 v; } vb;
                    vb.u = *reinterpret_cast<const uint2*>(&vt[ve]);
                    acc[n] = mfma16(pa.v, vb.v, acc[n]);
                }
            }

            __syncthreads();   // single barrier: buf[cur^1] ready, buf[cur] free
        }

        // ---- epilogue: fetch l for q=lg*4+r via shfl, write O
        float linv[4];
        #pragma unroll
        for (int r = 0; r < 4; ++r)
            linv[r] = 1.f / __shfl(l_, lg * 4 + r, 64);
        float* Ob = O + ((size_t)b * LL + qbase) * DD;
        #pragma unroll
        for (int n = 0; n < 4; ++n) {
            #pragma unroll
            for (int r = 0; r < 4; ++r) {
                Ob[(size_t)(lg * 4 + r) * DD + n * 16 + lq] = acc[n][r] * linv[r];
            }
        }
    }
}

extern "C" void kernel_launch(void* const* d_in, const int* in_sizes, int n_in,
                              void* d_out, int out_size, void* d_ws, size_t ws_size,
                              hipStream_t stream) {
    const float* Q = (const float*)d_in[0];
    const float* K = (const float*)d_in[1];
    const float* V = (const float*)d_in[2];
    const int* vlen = (const int*)d_in[3];
    float* O = (float*)d_out;
    int* ws = (int*)d_ws;

    init_ctr_kernel<<<1, 64, 0, stream>>>(vlen, ws);
    attn_mfma_kernel<<<GRID, 256, 0, stream>>>(Q, K, V, vlen, O, ws);
}

// Round 9
// 76.820 us; speedup vs baseline: 1.0636x; 1.0636x over previous
//
#include <hip/hip_runtime.h>
#include <hip/hip_bf16.h>
#include <math.h>

// DotProductAttention B=32, L=2048, D=64, fp32 IO, per-batch key-length mask.
// Round 9: round-6 core + single-barrier double-buffered K/V. Nothing else.
//  - Round 6 (71.9us) P layout retained: wave-private [16][64] pswz buffer,
//    16x16x32 PV MFMA (round 8's 16x16x16 halved FLOP/instr -> regressed).
//  - K/V double-buffered: stage(t+1 from regs), prefetch(t+2), compute(t),
//    ONE barrier per k-tile. P is wave-private -> needs no barrier.
//  - LDS 40KB/block x3/CU = 120KB; GRID 768 (queue keeps ~2x slack).
//  - LPT queue (longest batches first) retained.

#define BB 32
#define LL 2048
#define DD 64
#define QBLK 64
#define KBLK 64
#define NTILES (BB * (LL / QBLK))   // 1024
#define GRID 768

typedef __attribute__((ext_vector_type(8))) short bf16x8;
typedef __attribute__((ext_vector_type(4))) float f32x4;

static __device__ __forceinline__ short f2bf(float f) {
    __hip_bfloat16 h = __float2bfloat16(f);
    return *reinterpret_cast<short*>(&h);
}
static __device__ __forceinline__ unsigned pk2(float a, float b) {
    return (unsigned)(unsigned short)f2bf(a) | ((unsigned)(unsigned short)f2bf(b) << 16);
}
static __device__ __forceinline__ float exp2c(float x) {
    return __builtin_amdgcn_exp2f(x);
}
static __device__ __forceinline__ int kswz(int row) { return (row & 7) << 3; }
static __device__ __forceinline__ int vswz(int d)   { return ((d ^ (d >> 2)) & 7) << 3; }
static __device__ __forceinline__ int pswz(int row) { return (((row & 7) ^ (row >> 3)) & 7) << 3; }

// ws[0] = queue counter; ws[1..32] = batch ids sorted by valid_len desc
__global__ void init_ctr_kernel(const int* __restrict__ vlen, int* __restrict__ ws) {
    int t = threadIdx.x;
    if (t == 0) ws[0] = 0;
    if (t < BB) {
        int v = vlen[t];
        int rank = 0;
        for (int j = 0; j < BB; ++j) {
            int vj = vlen[j];
            rank += (vj > v) || (vj == v && j < t);
        }
        ws[1 + rank] = t;
    }
}

__global__ __launch_bounds__(256, 2) void attn_mfma_kernel(
    const float* __restrict__ Q, const float* __restrict__ K,
    const float* __restrict__ V, const int* __restrict__ vlen,
    float* __restrict__ O, int* __restrict__ ws)
{
    __shared__ __align__(16) short Ks[2][KBLK * DD];   // [buf][k][d], kswz
    __shared__ __align__(16) short Vt[2][DD * KBLK];   // [buf][d][k], vswz
    __shared__ __align__(16) short Pl[4][16 * KBLK];   // per-wave [q][k], pswz
    __shared__ int s_tile;

    int* ctr = ws;
    const int* order = ws + 1;

    const int tid  = threadIdx.x;
    const int wid  = tid >> 6;
    const int lane = tid & 63;
    const int lq   = lane & 15;
    const int lg   = lane >> 4;

    // V staging mapping: thread owns 4 k-rows x 4 d-cols
    const int vd4 = (tid & 15) * 4;     // d base
    const int vkr = (tid >> 4) * 4;     // k base

    const float QSCALE = 0.125f * 1.44269504088896341f;  // 1/sqrt(D) * log2(e)

    float4 kpre[4], vpre[4];

    for (;;) {
        __syncthreads();                 // prev tile fully done before s_tile reuse
        if (tid == 0) s_tile = atomicAdd(ctr, 1);
        __syncthreads();
        const int tile = s_tile;
        if (tile >= NTILES) break;

        const int b     = order[tile >> 5];   // LPT: longest batches first
        const int qt    = tile & 31;
        const int qbase = qt * QBLK + wid * 16;
        const int valid = vlen[b];
        const int ntiles = (valid + KBLK - 1) / KBLK;

        const float4* Kg4 = reinterpret_cast<const float4*>(K + (size_t)b * LL * DD);
        const float4* Vg4 = reinterpret_cast<const float4*>(V + (size_t)b * LL * DD);

        // prefetch K/V k-tile `t` into kpre/vpre
        auto prefetch = [&](int t) {
            const int base4 = t * KBLK * (DD / 4);
            #pragma unroll
            for (int i = 0; i < 4; ++i) kpre[i] = Kg4[base4 + tid + i * 256];
            #pragma unroll
            for (int r = 0; r < 4; ++r) vpre[r] = Vg4[base4 + (vkr + r) * 16 + (tid & 15)];
        };
        // write kpre/vpre (fp32) -> LDS buf (bf16, swizzled)
        auto stage = [&](int buf) {
            short* ks = &Ks[buf][0];
            short* vt = &Vt[buf][0];
            #pragma unroll
            for (int i = 0; i < 4; ++i) {
                int idx = tid + i * 256;
                int kr  = idx >> 4;
                int dc  = (idx & 15) * 4;
                float4 kv = kpre[i];
                int e = (kr * 64 + dc) ^ kswz(kr);
                *reinterpret_cast<uint2*>(&ks[e]) =
                    make_uint2(pk2(kv.x, kv.y), pk2(kv.z, kv.w));
            }
            float4 v0 = vpre[0], v1 = vpre[1], v2 = vpre[2], v3 = vpre[3];
            int e0 = ((vd4 + 0) * 64 + vkr) ^ vswz(vd4 + 0);
            *reinterpret_cast<uint2*>(&vt[e0]) = make_uint2(pk2(v0.x, v1.x), pk2(v2.x, v3.x));
            int e1 = ((vd4 + 1) * 64 + vkr) ^ vswz(vd4 + 1);
            *reinterpret_cast<uint2*>(&vt[e1]) = make_uint2(pk2(v0.y, v1.y), pk2(v2.y, v3.y));
            int e2 = ((vd4 + 2) * 64 + vkr) ^ vswz(vd4 + 2);
            *reinterpret_cast<uint2*>(&vt[e2]) = make_uint2(pk2(v0.z, v1.z), pk2(v2.z, v3.z));
            int e3 = ((vd4 + 3) * 64 + vkr) ^ vswz(vd4 + 3);
            *reinterpret_cast<uint2*>(&vt[e3]) = make_uint2(pk2(v0.w, v1.w), pk2(v2.w, v3.w));
        };

        // ---- Q B-frags (regs): lane holds Q[qbase+lq][ds*32 + lg*8 .. +7]
        bf16x8 qf[2];
        {
            const float* Qr = Q + ((size_t)b * LL + qbase + lq) * DD;
            #pragma unroll
            for (int ds_ = 0; ds_ < 2; ++ds_) {
                const float4* p4 = reinterpret_cast<const float4*>(Qr + ds_ * 32 + lg * 8);
                float4 a = p4[0], c = p4[1];
                bf16x8 f;
                f[0] = f2bf(a.x * QSCALE); f[1] = f2bf(a.y * QSCALE);
                f[2] = f2bf(a.z * QSCALE); f[3] = f2bf(a.w * QSCALE);
                f[4] = f2bf(c.x * QSCALE); f[5] = f2bf(c.y * QSCALE);
                f[6] = f2bf(c.z * QSCALE); f[7] = f2bf(c.w * QSCALE);
                qf[ds_] = f;
            }
        }

        f32x4 acc[4];                    // acc[n][r]: q=lg*4+r, d=n*16+lq
        #pragma unroll
        for (int n = 0; n < 4; ++n) acc[n] = (f32x4){0.f, 0.f, 0.f, 0.f};
        float m_ = -1e30f, l_ = 0.f;     // scalars for q = lq (k-major lanes)

        // ---- pipeline prologue: stage tile 0 into buf 0, prefetch tile 1
        prefetch(0);
        stage(0);
        if (ntiles > 1) prefetch(1);
        __syncthreads();                 // buf0 ready for all waves

        for (int kt = 0; kt < ntiles; ++kt) {
            const int cur = kt & 1;

            // ---- write next tile into other buffer; issue loads for t+2
            if (kt + 1 < ntiles) {
                stage(cur ^ 1);          // kpre/vpre hold tile kt+1 (landed)
                if (kt + 2 < ntiles) prefetch(kt + 2);
            }

            // ---- swapped QK^T: s[t][r] = S[k = kt*64+t*16+lg*4+r][q = lq]
            const short* ks = &Ks[cur][0];
            f32x4 s[4];
            #pragma unroll
            for (int t = 0; t < 4; ++t) {
                f32x4 a = (f32x4){0.f, 0.f, 0.f, 0.f};
                const int krow = t * 16 + lq;
                #pragma unroll
                for (int ds_ = 0; ds_ < 2; ++ds_) {
                    int e = (krow * 64 + ds_ * 32 + lg * 8) ^ kswz(krow);
                    bf16x8 kf = *reinterpret_cast<const bf16x8*>(&ks[e]);
                    a = __builtin_amdgcn_mfma_f32_16x16x32_bf16(kf, qf[ds_], a, 0, 0, 0);
                }
                s[t] = a;
            }

            // ---- mask (last partial tile only), in-lane row-max + 2 shfl
            const bool tail = (kt == ntiles - 1) && (valid & (KBLK - 1));
            if (tail) {
                #pragma unroll
                for (int t = 0; t < 4; ++t)
                    #pragma unroll
                    for (int r = 0; r < 4; ++r) {
                        int kg = kt * KBLK + t * 16 + lg * 4 + r;
                        if (kg >= valid) s[t][r] = -1e30f;
                    }
            }
            float mx = s[0][0];
            #pragma unroll
            for (int t = 0; t < 4; ++t)
                #pragma unroll
                for (int r = 0; r < 4; ++r) mx = fmaxf(mx, s[t][r]);
            mx = fmaxf(mx, __shfl_xor(mx, 16, 64));
            mx = fmaxf(mx, __shfl_xor(mx, 32, 64));

            // ---- defer-max (T13, log2 domain THR=8)
            if (__any(mx - m_ > 8.0f)) {
                float mnew = fmaxf(m_, mx);
                float corr = exp2c(m_ - mnew);
                m_ = mnew;
                l_ *= corr;
                #pragma unroll
                for (int r = 0; r < 4; ++r) {
                    float cq = __shfl(corr, lg * 4 + r, 64);   // corr for q=lg*4+r
                    #pragma unroll
                    for (int n = 0; n < 4; ++n) acc[n][r] *= cq;
                }
            }

            // ---- p = exp2(s - m), in-lane sum + 2 shfl
            float ls = 0.f;
            #pragma unroll
            for (int t = 0; t < 4; ++t)
                #pragma unroll
                for (int r = 0; r < 4; ++r) {
                    float p = exp2c(s[t][r] - m_);
                    s[t][r] = p;
                    ls += p;
                }
            ls += __shfl_xor(ls, 16, 64);
            ls += __shfl_xor(ls, 32, 64);
            l_ += ls;

            // ---- P -> wave-private LDS (bf16, pswz); no barrier needed
            short* Pw = &Pl[wid][0];
            #pragma unroll
            for (int t = 0; t < 4; ++t) {
                int e = (lq * 64 + t * 16 + lg * 4) ^ pswz(lq);
                *reinterpret_cast<uint2*>(&Pw[e]) =
                    make_uint2(pk2(s[t][0], s[t][1]), pk2(s[t][2], s[t][3]));
            }

            // ---- PV: acc[n] += P(16xK) * V(Kx16), per 32-k chunk
            const short* vt = &Vt[cur][0];
            #pragma unroll
            for (int ks_ = 0; ks_ < 2; ++ks_) {
                int pe = (lq * 64 + ks_ * 32 + lg * 8) ^ pswz(lq);
                bf16x8 pf = *reinterpret_cast<const bf16x8*>(&Pw[pe]);
                #pragma unroll
                for (int n = 0; n < 4; ++n) {
                    int drow = n * 16 + lq;
                    int ve = (drow * 64 + ks_ * 32 + lg * 8) ^ vswz(drow);
                    bf16x8 vf = *reinterpret_cast<const bf16x8*>(&vt[ve]);
                    acc[n] = __builtin_amdgcn_mfma_f32_16x16x32_bf16(pf, vf, acc[n], 0, 0, 0);
                }
            }

            __syncthreads();   // single barrier: buf[cur^1] ready, buf[cur] free
        }

        // ---- epilogue: fetch l for q=lg*4+r via shfl, write O
        float linv[4];
        #pragma unroll
        for (int r = 0; r < 4; ++r)
            linv[r] = 1.f / __shfl(l_, lg * 4 + r, 64);
        float* Ob = O + ((size_t)b * LL + qbase) * DD;
        #pragma unroll
        for (int n = 0; n < 4; ++n) {
            #pragma unroll
            for (int r = 0; r < 4; ++r) {
                Ob[(size_t)(lg * 4 + r) * DD + n * 16 + lq] = acc[n][r] * linv[r];
            }
        }
    }
}

extern "C" void kernel_launch(void* const* d_in, const int* in_sizes, int n_in,
                              void* d_out, int out_size, void* d_ws, size_t ws_size,
                              hipStream_t stream) {
    const float* Q = (const float*)d_in[0];
    const float* K = (const float*)d_in[1];
    const float* V = (const float*)d_in[2];
    const int* vlen = (const int*)d_in[3];
    float* O = (float*)d_out;
    int* ws = (int*)d_ws;

    init_ctr_kernel<<<1, 64, 0, stream>>>(vlen, ws);
    attn_mfma_kernel<<<GRID, 256, 0, stream>>>(Q, K, V, vlen, O, ws);
}